// Round 1
// baseline (176.646 us; speedup 1.0000x reference)
//
#include <hip/hip_runtime.h>
#include <math.h>

#define NB 64
#define NT 12
#define ND 256
#define NS 512
#define NV 512

__device__ __forceinline__ float gelu_exact(float x) {
    return 0.5f * x * (1.0f + erff(x * 0.70710678118654752f));
}
__device__ __forceinline__ float sigmoidf_(float x) {
    return 1.0f / (1.0f + __expf(-x));
}

// ---------------------------------------------------------------------------
// K1: gate MLPs. grid = (B batches x 2 gates) = 128 blocks, 256 threads.
// Thread j computes hidden column j for all T=12 events of batch b:
//   h[t][j] = sum_i ev[t][i] * W1[i][j]   (ev reads are wave-uniform -> s_load)
// then p[t] = gelu(h+b1[j]) * W2[j], block-reduce over j, sigmoid.
// ---------------------------------------------------------------------------
__global__ __launch_bounds__(256) void k_gates(
    const float* __restrict__ evidence,
    const float* __restrict__ Wmg1, const float* __restrict__ bmg1,
    const float* __restrict__ Wmg2, const float* __restrict__ bmg2,
    const float* __restrict__ Wsg1, const float* __restrict__ bsg1,
    const float* __restrict__ Wsg2, const float* __restrict__ bsg2,
    float* __restrict__ gates)  // [2][B*T]
{
    const int blk = blockIdx.x;
    const int b = blk >> 1, g = blk & 1;
    const int j = threadIdx.x;
    const float* __restrict__ W1 = g ? Wsg1 : Wmg1;
    const float* __restrict__ b1 = g ? bsg1 : bmg1;
    const float* __restrict__ W2 = g ? Wsg2 : Wmg2;
    const float* __restrict__ b2 = g ? bsg2 : bmg2;
    const float* __restrict__ ev = evidence + b * (NT * ND);

    float h[NT];
    #pragma unroll
    for (int t = 0; t < NT; ++t) h[t] = 0.0f;

    #pragma unroll 8
    for (int i = 0; i < ND; ++i) {
        float w = W1[i * ND + j];
        #pragma unroll
        for (int t = 0; t < NT; ++t) h[t] += ev[t * ND + i] * w;
    }

    const float b1j = b1[j], w2j = W2[j];
    float p[NT];
    #pragma unroll
    for (int t = 0; t < NT; ++t) p[t] = gelu_exact(h[t] + b1j) * w2j;

    __shared__ float red[4][NT];
    const int lane = threadIdx.x & 63, wv = threadIdx.x >> 6;
    #pragma unroll
    for (int t = 0; t < NT; ++t) {
        float v = p[t];
        #pragma unroll
        for (int off = 32; off > 0; off >>= 1) v += __shfl_down(v, off, 64);
        if (lane == 0) red[wv][t] = v;
    }
    __syncthreads();
    if (threadIdx.x < NT) {
        float s = red[0][threadIdx.x] + red[1][threadIdx.x] +
                  red[2][threadIdx.x] + red[3][threadIdx.x] + b2[0];
        gates[g * (NB * NT) + b * NT + threadIdx.x] = sigmoidf_(s);
    }
}

// ---------------------------------------------------------------------------
// K2: sparse graph-memory readout. grid = 64 blocks (one per batch), 256 thr.
// map_mem / step_mem are never materialized: each holds <=12 nonzeros/batch.
// Walk propagated via dense LDS vector + 12-thread atomic scatter per stage;
// acc_s / acc_v kept as compact (idx, weight) lists, then <=49 row gathers.
// ---------------------------------------------------------------------------
__global__ __launch_bounds__(256) void k_readout(
    const int* __restrict__ marker, const int* __restrict__ srci,
    const int* __restrict__ srcv, const int* __restrict__ tsymi,
    const int* __restrict__ tsymv, const int* __restrict__ tvali,
    const int* __restrict__ tvalv, const int* __restrict__ qidx,
    const int* __restrict__ qvld,
    const float* __restrict__ symbol_emb, const float* __restrict__ value_emb,
    const float* __restrict__ gates,
    float* __restrict__ gs)   // [B][512] = concat(acc_s, acc_v@value_emb)
{
    const int b = blockIdx.x, tid = threadIdx.x;
    __shared__ float walk[NS], nxt[NS];
    __shared__ int   esrc[NT], etsym[NT], etval[NT];
    __shared__ float mapw[NT], stepw[NT];
    __shared__ int   sidx[64]; __shared__ float sval[64];
    __shared__ int   vidx[64]; __shared__ float vval[64];
    __shared__ int   scnt, vcnt;

    walk[tid] = 0.f; walk[tid + 256] = 0.f;
    nxt[tid] = 0.f;  nxt[tid + 256] = 0.f;
    if (tid == 0) { scnt = 0; vcnt = 0; }
    if (tid < NT) {
        int e = b * NT + tid;
        int mk = marker[e];
        int sv_ = srcv[e], tsv_ = tsymv[e], tvv_ = tvalv[e];
        esrc[tid]  = min(max(srci[e], 0), NS - 1);
        etsym[tid] = min(max(tsymi[e], 0), NS - 1);
        etval[tid] = min(max(tvali[e], 0), NV - 1);
        bool mmask = ((mk == 0) || (mk == 1)) && (sv_ > 0) && (tvv_ > 0);
        bool smask = (mk == 2) && (sv_ > 0) && (tsv_ > 0);
        mapw[tid]  = mmask ? gates[0 * (NB * NT) + e] : 0.f;
        stepw[tid] = smask ? gates[1 * (NB * NT) + e] : 0.f;
    }
    __syncthreads();
    if (tid == 0) {
        int qc = min(max(qidx[b], 0), NS - 1);
        float qv = (float)qvld[b];
        walk[qc] = qv;
        if (qv != 0.f) { sidx[0] = qc; sval[0] = qv; scnt = 1; }
    }
    __syncthreads();
    // stage 0: acc_v contribution from initial walk
    if (tid < NT) {
        float c = walk[esrc[tid]] * mapw[tid];
        if (c != 0.f) { int k = atomicAdd(&vcnt, 1); vidx[k] = etval[tid]; vval[k] = c; }
    }
    __syncthreads();
    for (int stp = 0; stp < 3; ++stp) {
        // walk = walk @ step_mem (sparse: per-event scatter using OLD walk)
        if (tid < NT) {
            float c = walk[esrc[tid]] * stepw[tid];
            if (c != 0.f) {
                atomicAdd(&nxt[etsym[tid]], c);
                int k = atomicAdd(&scnt, 1); sidx[k] = etsym[tid]; sval[k] = c;
            }
        }
        __syncthreads();
        { float a0 = nxt[tid];       walk[tid] = a0;       nxt[tid] = 0.f;
          float a1 = nxt[tid + 256]; walk[tid + 256] = a1; nxt[tid + 256] = 0.f; }
        __syncthreads();
        // acc_v += walk @ map_mem (with updated walk)
        if (tid < NT) {
            float c = walk[esrc[tid]] * mapw[tid];
            if (c != 0.f) { int k = atomicAdd(&vcnt, 1); vidx[k] = etval[tid]; vval[k] = c; }
        }
        __syncthreads();
    }
    const int ns = scnt, nv = vcnt;
    float accs = 0.f, accv = 0.f;
    for (int k = 0; k < ns; ++k) accs += sval[k] * symbol_emb[sidx[k] * ND + tid];
    for (int k = 0; k < nv; ++k) accv += vval[k] * value_emb[vidx[k] * ND + tid];
    gs[b * 512 + tid]       = accs;
    gs[b * 512 + 256 + tid] = accv;
}

// ---------------------------------------------------------------------------
// K3: first layers of output/feedback MLPs. grid = 2 mats x 8 btiles x 4 jslices
// = 64 blocks, 256 threads (64 j-lanes x 4 b-subgroups, 2 batches/thread).
// H[m][b][j] = gelu(sum_i gs[b][i] * W1[i][j] + b1[j])
// ---------------------------------------------------------------------------
__global__ __launch_bounds__(256) void k_mlp1(
    const float* __restrict__ gs,
    const float* __restrict__ Wo1, const float* __restrict__ bo1,
    const float* __restrict__ Wf1, const float* __restrict__ bf1,
    float* __restrict__ H)  // [2][B][256], m=0 -> Ho (logits), m=1 -> Hf
{
    const int blk = blockIdx.x;
    const int m = blk >> 5;
    const int r = blk & 31;
    const int bt = r >> 2, js = r & 3;
    const int jl = threadIdx.x & 63;
    const int bsub = __builtin_amdgcn_readfirstlane(threadIdx.x >> 6);
    const int j = js * 64 + jl;
    const int b0 = bt * 8 + bsub * 2, b1_ = b0 + 1;
    const float* __restrict__ W1   = m ? Wf1 : Wo1;
    const float* __restrict__ bias = m ? bf1 : bo1;
    const float* __restrict__ x0 = gs + b0 * 512;
    const float* __restrict__ x1 = gs + b1_ * 512;
    float a0 = 0.f, a1 = 0.f;
    #pragma unroll 8
    for (int i = 0; i < 512; ++i) {
        float w = W1[i * 256 + j];
        a0 += x0[i] * w; a1 += x1[i] * w;
    }
    float bj = bias[j];
    H[m * (NB * 256) + b0 * 256 + j]  = gelu_exact(a0 + bj);
    H[m * (NB * 256) + b1_ * 256 + j] = gelu_exact(a1 + bj);
}

// ---------------------------------------------------------------------------
// K4: second layers. blocks 0..63: logits (64x512); 64..95: feedback (64x256).
// ---------------------------------------------------------------------------
__global__ __launch_bounds__(256) void k_mlp2(
    const float* __restrict__ H,
    const float* __restrict__ Wo2, const float* __restrict__ bo2,
    const float* __restrict__ Wf2, const float* __restrict__ bf2,
    float* __restrict__ out)  // [logits 64*512 | feedback 64*256]
{
    const int blk = blockIdx.x;
    const int jl = threadIdx.x & 63;
    const int bsub = __builtin_amdgcn_readfirstlane(threadIdx.x >> 6);
    if (blk < 64) {
        const int bt = blk >> 3, vs = blk & 7;
        const int v = vs * 64 + jl;
        const int b0 = bt * 8 + bsub * 2, b1_ = b0 + 1;
        const float* __restrict__ h0 = H + b0 * 256;
        const float* __restrict__ h1 = H + b1_ * 256;
        float a0 = 0.f, a1 = 0.f;
        #pragma unroll 8
        for (int k = 0; k < 256; ++k) {
            float w = Wo2[k * 512 + v];
            a0 += h0[k] * w; a1 += h1[k] * w;
        }
        float bv = bo2[v];
        out[b0 * 512 + v]  = a0 + bv;
        out[b1_ * 512 + v] = a1 + bv;
    } else {
        const int r = blk - 64;
        const int bt = r >> 2, ds = r & 3;
        const int d = ds * 64 + jl;
        const int b0 = bt * 8 + bsub * 2, b1_ = b0 + 1;
        const float* __restrict__ h0 = H + (NB * 256) + b0 * 256;
        const float* __restrict__ h1 = H + (NB * 256) + b1_ * 256;
        float a0 = 0.f, a1 = 0.f;
        #pragma unroll 8
        for (int k = 0; k < 256; ++k) {
            float w = Wf2[k * 256 + d];
            a0 += h0[k] * w; a1 += h1[k] * w;
        }
        float bd = bf2[d];
        out[NB * NV + b0 * 256 + d]  = a0 + bd;
        out[NB * NV + b1_ * 256 + d] = a1 + bd;
    }
}

extern "C" void kernel_launch(void* const* d_in, const int* in_sizes, int n_in,
                              void* d_out, int out_size, void* d_ws, size_t ws_size,
                              hipStream_t stream) {
    const int* event_marker       = (const int*)d_in[0];
    const int* source_idx         = (const int*)d_in[1];
    const int* source_valid       = (const int*)d_in[2];
    const int* target_symbol_idx  = (const int*)d_in[3];
    const int* target_symbol_vld  = (const int*)d_in[4];
    const int* target_value_idx   = (const int*)d_in[5];
    const int* target_value_vld   = (const int*)d_in[6];
    const int* query_idx          = (const int*)d_in[7];
    const int* query_valid        = (const int*)d_in[8];
    const float* evidence   = (const float*)d_in[9];
    const float* symbol_emb = (const float*)d_in[10];
    const float* value_emb  = (const float*)d_in[11];
    const float* Wmg1 = (const float*)d_in[12]; const float* bmg1 = (const float*)d_in[13];
    const float* Wmg2 = (const float*)d_in[14]; const float* bmg2 = (const float*)d_in[15];
    const float* Wsg1 = (const float*)d_in[16]; const float* bsg1 = (const float*)d_in[17];
    const float* Wsg2 = (const float*)d_in[18]; const float* bsg2 = (const float*)d_in[19];
    const float* Wf1  = (const float*)d_in[20]; const float* bf1  = (const float*)d_in[21];
    const float* Wf2  = (const float*)d_in[22]; const float* bf2  = (const float*)d_in[23];
    const float* Wo1  = (const float*)d_in[24]; const float* bo1  = (const float*)d_in[25];
    const float* Wo2  = (const float*)d_in[26]; const float* bo2  = (const float*)d_in[27];

    float* ws    = (float*)d_ws;
    float* gates = ws;                  // [2][768]   = 1536 floats
    float* gs    = ws + 2048;           // [64][512]  = 32768 floats
    float* H     = ws + 2048 + 32768;   // [2][64][256] = 32768 floats

    k_gates<<<dim3(128), dim3(256), 0, stream>>>(
        evidence, Wmg1, bmg1, Wmg2, bmg2, Wsg1, bsg1, Wsg2, bsg2, gates);
    k_readout<<<dim3(64), dim3(256), 0, stream>>>(
        event_marker, source_idx, source_valid, target_symbol_idx,
        target_symbol_vld, target_value_idx, target_value_vld,
        query_idx, query_valid, symbol_emb, value_emb, gates, gs);
    k_mlp1<<<dim3(64), dim3(256), 0, stream>>>(gs, Wo1, bo1, Wf1, bf1, H);
    k_mlp2<<<dim3(96), dim3(256), 0, stream>>>(H, Wo2, bo2, Wf2, bf2, (float*)d_out);
}

// Round 2
// 164.026 us; speedup vs baseline: 1.0769x; 1.0769x over previous
//
#include <hip/hip_runtime.h>
#include <math.h>

#define NB 64
#define NT 12
#define ND 256
#define NS 512
#define NV 512

__device__ __forceinline__ float gelu_exact(float x) {
    return 0.5f * x * (1.0f + erff(x * 0.70710678118654752f));
}
__device__ __forceinline__ float sigmoidf_(float x) {
    return 1.0f / (1.0f + __expf(-x));
}

// ---------------------------------------------------------------------------
// K_A: fused gate-MLPs + sparse graph readout. grid = 64 (one block/batch),
// 512 threads. Phase 1: waves 0-3 compute map-gate, waves 4-7 step-gate
// (thread j = hidden column, full i-loop, uniform evidence reads -> s_load).
// Gates stay in LDS. Phase 2: sparse walk propagation (<=12 nonzeros per
// memory) + split-half embedding gathers with 4-wide prefetch.
// ---------------------------------------------------------------------------
__global__ __launch_bounds__(512) void k_gates_readout(
    const int* __restrict__ marker, const int* __restrict__ srci,
    const int* __restrict__ srcv, const int* __restrict__ tsymi,
    const int* __restrict__ tsymv, const int* __restrict__ tvali,
    const int* __restrict__ tvalv, const int* __restrict__ qidx,
    const int* __restrict__ qvld,
    const float* __restrict__ evidence,
    const float* __restrict__ symbol_emb, const float* __restrict__ value_emb,
    const float* __restrict__ Wmg1, const float* __restrict__ bmg1,
    const float* __restrict__ Wmg2, const float* __restrict__ bmg2,
    const float* __restrict__ Wsg1, const float* __restrict__ bsg1,
    const float* __restrict__ Wsg2, const float* __restrict__ bsg2,
    float* __restrict__ gs)   // [B][512] = concat(acc_s, acc_v@value_emb)
{
    const int b = blockIdx.x, tid = threadIdx.x;
    const int g = tid >> 8;          // wave-uniform: waves 0-3 -> 0, 4-7 -> 1
    const int j = tid & 255;
    const int lane = tid & 63, wv = tid >> 6;

    __shared__ float red[8][NT];
    __shared__ float gate_s[2][NT];

    // ---- phase 1: gates ----
    {
        const float* __restrict__ W1 = g ? Wsg1 : Wmg1;
        const float* __restrict__ b1 = g ? bsg1 : bmg1;
        const float* __restrict__ W2 = g ? Wsg2 : Wmg2;
        const float* __restrict__ ev = evidence + b * (NT * ND);

        float h[NT];
        #pragma unroll
        for (int t = 0; t < NT; ++t) h[t] = 0.0f;

        #pragma unroll 8
        for (int i = 0; i < ND; ++i) {
            float w = W1[i * ND + j];
            #pragma unroll
            for (int t = 0; t < NT; ++t) h[t] += ev[t * ND + i] * w;
        }

        const float b1j = b1[j], w2j = W2[j];
        #pragma unroll
        for (int t = 0; t < NT; ++t) {
            float v = gelu_exact(h[t] + b1j) * w2j;
            #pragma unroll
            for (int off = 32; off > 0; off >>= 1) v += __shfl_down(v, off, 64);
            if (lane == 0) red[wv][t] = v;
        }
    }
    __syncthreads();
    if (tid < 24) {
        int gg = tid / NT, tt = tid - gg * NT;
        float s = red[gg * 4 + 0][tt] + red[gg * 4 + 1][tt] +
                  red[gg * 4 + 2][tt] + red[gg * 4 + 3][tt] +
                  (gg ? bsg2[0] : bmg2[0]);
        gate_s[gg][tt] = sigmoidf_(s);
    }

    // ---- phase 2: sparse readout ----
    __shared__ float walk[NS], nxt[NS];
    __shared__ int   esrc[NT], etsym[NT], etval[NT];
    __shared__ float mapw[NT], stepw[NT];
    __shared__ int   sidx[64]; __shared__ float sval[64];
    __shared__ int   vidx[64]; __shared__ float vval[64];
    __shared__ int   scnt, vcnt;

    walk[tid] = 0.f; nxt[tid] = 0.f;
    if (tid == 0) { scnt = 0; vcnt = 0; }
    if (tid >= 256 && tid < 256 + NT) {
        int t = tid - 256;
        int e = b * NT + t;
        int mk = marker[e];
        int sv_ = srcv[e], tsv_ = tsymv[e], tvv_ = tvalv[e];
        esrc[t]  = min(max(srci[e], 0), NS - 1);
        etsym[t] = min(max(tsymi[e], 0), NS - 1);
        etval[t] = min(max(tvali[e], 0), NV - 1);
        // store masks as +/-0 sentinel: use separate arrays written after gates known
        mapw[t]  = (((mk == 0) || (mk == 1)) && (sv_ > 0) && (tvv_ > 0)) ? 1.f : 0.f;
        stepw[t] = ((mk == 2) && (sv_ > 0) && (tsv_ > 0)) ? 1.f : 0.f;
    }
    __syncthreads();
    if (tid < NT) {   // multiply masks by gates (gate_s valid after barrier)
        mapw[tid]  *= gate_s[0][tid];
        stepw[tid] *= gate_s[1][tid];
    }
    if (tid == 256) {
        int qc = min(max(qidx[b], 0), NS - 1);
        float qv = (float)qvld[b];
        walk[qc] = qv;
        if (qv != 0.f) { sidx[0] = qc; sval[0] = qv; scnt = 1; }
    }
    __syncthreads();
    // stage 0: acc_v contribution from initial walk
    if (tid < NT) {
        float c = walk[esrc[tid]] * mapw[tid];
        if (c != 0.f) { int k = atomicAdd(&vcnt, 1); vidx[k] = etval[tid]; vval[k] = c; }
    }
    __syncthreads();
    for (int stp = 0; stp < 3; ++stp) {
        if (tid < NT) {
            float c = walk[esrc[tid]] * stepw[tid];
            if (c != 0.f) {
                atomicAdd(&nxt[etsym[tid]], c);
                int k = atomicAdd(&scnt, 1); sidx[k] = etsym[tid]; sval[k] = c;
            }
        }
        __syncthreads();
        { float a = nxt[tid]; walk[tid] = a; nxt[tid] = 0.f; }
        __syncthreads();
        if (tid < NT) {
            float c = walk[esrc[tid]] * mapw[tid];
            if (c != 0.f) { int k = atomicAdd(&vcnt, 1); vidx[k] = etval[tid]; vval[k] = c; }
        }
        __syncthreads();
    }
    // gathers: threads 0-255 -> symbol/acc_s, threads 256-511 -> value/acc_v
    const int d = tid & 255;
    const float* __restrict__ emb  = (tid < 256) ? symbol_emb : value_emb;
    const int*   idxl = (tid < 256) ? sidx : vidx;
    const float* vall = (tid < 256) ? sval : vval;
    const int n = (tid < 256) ? scnt : vcnt;
    float acc = 0.f;
    int k = 0;
    for (; k + 4 <= n; k += 4) {
        int   i0 = idxl[k],     i1 = idxl[k + 1], i2 = idxl[k + 2], i3 = idxl[k + 3];
        float w0 = vall[k],     w1 = vall[k + 1], w2 = vall[k + 2], w3 = vall[k + 3];
        float r0 = emb[i0 * ND + d], r1 = emb[i1 * ND + d];
        float r2 = emb[i2 * ND + d], r3 = emb[i3 * ND + d];
        acc += w0 * r0; acc += w1 * r1; acc += w2 * r2; acc += w3 * r3;
    }
    for (; k < n; ++k) acc += vall[k] * emb[idxl[k] * ND + d];
    gs[b * 512 + (tid < 256 ? 0 : 256) + d] = acc;
}

// ---------------------------------------------------------------------------
// K_B: first MLP layers. grid = (2 mats x 4 j-slices x 8 b-tiles) = 64 blocks,
// 512 threads: i-dimension split across thread halves (ih), LDS pair-reduce.
// H[m][b][j] = gelu(sum_i gs[b][i] * W1[i][j] + b1[j])
// ---------------------------------------------------------------------------
__global__ __launch_bounds__(512) void k_mlp1(
    const float* __restrict__ gs,
    const float* __restrict__ Wo1, const float* __restrict__ bo1,
    const float* __restrict__ Wf1, const float* __restrict__ bf1,
    float* __restrict__ H)  // [2][B][256]
{
    const int blk = blockIdx.x;
    const int m = blk >> 5;
    const int r = blk & 31;
    const int js = r >> 3, bt = r & 7;
    const int tid = threadIdx.x;
    const int lane = tid & 63;
    const int bsub = (tid >> 6) & 3;
    const int ih = tid >> 8;
    const int j = js * 64 + lane;
    const int b0 = bt * 8 + bsub * 2, b1_ = b0 + 1;

    const float* __restrict__ W1   = (m ? Wf1 : Wo1) + ih * 256 * 256;
    const float* __restrict__ bias = m ? bf1 : bo1;
    const float* __restrict__ x0 = gs + b0 * 512 + ih * 256;
    const float* __restrict__ x1 = gs + b1_ * 512 + ih * 256;

    float a0 = 0.f, a1 = 0.f;
    #pragma unroll 8
    for (int i = 0; i < 256; ++i) {
        float w = W1[i * 256 + j];
        a0 += x0[i] * w; a1 += x1[i] * w;
    }
    __shared__ float part[256][2];
    if (ih == 1) { part[tid & 255][0] = a0; part[tid & 255][1] = a1; }
    __syncthreads();
    if (ih == 0) {
        float bj = bias[j];
        H[m * (NB * 256) + b0 * 256 + j]  = gelu_exact(a0 + part[tid][0] + bj);
        H[m * (NB * 256) + b1_ * 256 + j] = gelu_exact(a1 + part[tid][1] + bj);
    }
}

// ---------------------------------------------------------------------------
// K_C: second MLP layers. blocks 0..63: logits (64x512); 64..95: feedback
// (64x256). 512 threads, k-split across halves + LDS pair-reduce.
// ---------------------------------------------------------------------------
__global__ __launch_bounds__(512) void k_mlp2(
    const float* __restrict__ H,
    const float* __restrict__ Wo2, const float* __restrict__ bo2,
    const float* __restrict__ Wf2, const float* __restrict__ bf2,
    float* __restrict__ out)  // [logits 64*512 | feedback 64*256]
{
    const int blk = blockIdx.x;
    const int tid = threadIdx.x;
    const int lane = tid & 63;
    const int bsub = (tid >> 6) & 3;
    const int ih = tid >> 8;
    __shared__ float part[256][2];

    if (blk < 64) {
        const int bt = blk >> 3, vs = blk & 7;
        const int v = vs * 64 + lane;
        const int b0 = bt * 8 + bsub * 2, b1_ = b0 + 1;
        const float* __restrict__ h0 = H + b0 * 256 + ih * 128;
        const float* __restrict__ h1 = H + b1_ * 256 + ih * 128;
        const float* __restrict__ Wp = Wo2 + ih * 128 * 512;
        float a0 = 0.f, a1 = 0.f;
        #pragma unroll 8
        for (int k = 0; k < 128; ++k) {
            float w = Wp[k * 512 + v];
            a0 += h0[k] * w; a1 += h1[k] * w;
        }
        if (ih == 1) { part[tid & 255][0] = a0; part[tid & 255][1] = a1; }
        __syncthreads();
        if (ih == 0) {
            float bv = bo2[v];
            out[b0 * 512 + v]  = a0 + part[tid][0] + bv;
            out[b1_ * 512 + v] = a1 + part[tid][1] + bv;
        }
    } else {
        const int r = blk - 64;
        const int bt = r >> 2, ds = r & 3;
        const int d = ds * 64 + lane;
        const int b0 = bt * 8 + bsub * 2, b1_ = b0 + 1;
        const float* __restrict__ h0 = H + (NB * 256) + b0 * 256 + ih * 128;
        const float* __restrict__ h1 = H + (NB * 256) + b1_ * 256 + ih * 128;
        const float* __restrict__ Wp = Wf2 + ih * 128 * 256;
        float a0 = 0.f, a1 = 0.f;
        #pragma unroll 8
        for (int k = 0; k < 128; ++k) {
            float w = Wp[k * 256 + d];
            a0 += h0[k] * w; a1 += h1[k] * w;
        }
        if (ih == 1) { part[tid & 255][0] = a0; part[tid & 255][1] = a1; }
        __syncthreads();
        if (ih == 0) {
            float bd = bf2[d];
            out[NB * NV + b0 * 256 + d]  = a0 + part[tid][0] + bd;
            out[NB * NV + b1_ * 256 + d] = a1 + part[tid][1] + bd;
        }
    }
}

extern "C" void kernel_launch(void* const* d_in, const int* in_sizes, int n_in,
                              void* d_out, int out_size, void* d_ws, size_t ws_size,
                              hipStream_t stream) {
    const int* event_marker       = (const int*)d_in[0];
    const int* source_idx         = (const int*)d_in[1];
    const int* source_valid       = (const int*)d_in[2];
    const int* target_symbol_idx  = (const int*)d_in[3];
    const int* target_symbol_vld  = (const int*)d_in[4];
    const int* target_value_idx   = (const int*)d_in[5];
    const int* target_value_vld   = (const int*)d_in[6];
    const int* query_idx          = (const int*)d_in[7];
    const int* query_valid        = (const int*)d_in[8];
    const float* evidence   = (const float*)d_in[9];
    const float* symbol_emb = (const float*)d_in[10];
    const float* value_emb  = (const float*)d_in[11];
    const float* Wmg1 = (const float*)d_in[12]; const float* bmg1 = (const float*)d_in[13];
    const float* Wmg2 = (const float*)d_in[14]; const float* bmg2 = (const float*)d_in[15];
    const float* Wsg1 = (const float*)d_in[16]; const float* bsg1 = (const float*)d_in[17];
    const float* Wsg2 = (const float*)d_in[18]; const float* bsg2 = (const float*)d_in[19];
    const float* Wf1  = (const float*)d_in[20]; const float* bf1  = (const float*)d_in[21];
    const float* Wf2  = (const float*)d_in[22]; const float* bf2  = (const float*)d_in[23];
    const float* Wo1  = (const float*)d_in[24]; const float* bo1  = (const float*)d_in[25];
    const float* Wo2  = (const float*)d_in[26]; const float* bo2  = (const float*)d_in[27];

    float* ws = (float*)d_ws;
    float* gs = ws;            // [64][512]    = 32768 floats
    float* H  = ws + 32768;    // [2][64][256] = 32768 floats

    k_gates_readout<<<dim3(64), dim3(512), 0, stream>>>(
        event_marker, source_idx, source_valid, target_symbol_idx,
        target_symbol_vld, target_value_idx, target_value_vld,
        query_idx, query_valid, evidence, symbol_emb, value_emb,
        Wmg1, bmg1, Wmg2, bmg2, Wsg1, bsg1, Wsg2, bsg2, gs);
    k_mlp1<<<dim3(64), dim3(512), 0, stream>>>(gs, Wo1, bo1, Wf1, bf1, H);
    k_mlp2<<<dim3(96), dim3(512), 0, stream>>>(H, Wo2, bo2, Wf2, bf2, (float*)d_out);
}

// Round 3
// 155.004 us; speedup vs baseline: 1.1396x; 1.0582x over previous
//
#include <hip/hip_runtime.h>
#include <math.h>

#define NB 64
#define NT 12
#define ND 256
#define NS 512
#define NV 512

__device__ __forceinline__ float gelu_exact(float x) {
    return 0.5f * x * (1.0f + erff(x * 0.70710678118654752f));
}
__device__ __forceinline__ float sigmoidf_(float x) {
    return 1.0f / (1.0f + __expf(-x));
}

// ---------------------------------------------------------------------------
// K1: gate MLPs. grid = (b(64) x gate(2) x t-half(2)) = 256 blocks,
// 1024 threads = (j 0..255) x (ih 0..3 : 64-row i-chunk). Full-chip, 16 waves
// per CU. Per-CU cost: L2 weight stream 256KB (~4.3K cyc) > VALU 3.1K cyc ->
// L2-BW bound ~2us. LDS reduce over ih, then j-reduction, sigmoid, store.
// ---------------------------------------------------------------------------
__global__ __launch_bounds__(1024) void k_gates(
    const float* __restrict__ evidence,
    const float* __restrict__ Wmg1, const float* __restrict__ bmg1,
    const float* __restrict__ Wmg2, const float* __restrict__ bmg2,
    const float* __restrict__ Wsg1, const float* __restrict__ bsg1,
    const float* __restrict__ Wsg2, const float* __restrict__ bsg2,
    float* __restrict__ gates)  // [2][B*T]
{
    const int blk = blockIdx.x;
    const int b  = blk >> 2;
    const int g  = (blk >> 1) & 1;
    const int th = blk & 1;
    const int t0 = th * 6;
    const int tid = threadIdx.x;
    const int j = tid & 255;
    const int ih = tid >> 8;           // 0..3
    const int lane = tid & 63, wv = tid >> 6;

    __shared__ float part[3][6][256];
    __shared__ float red[4][6];

    const float* __restrict__ W1 = g ? Wsg1 : Wmg1;
    const float* __restrict__ b1 = g ? bsg1 : bmg1;
    const float* __restrict__ W2 = g ? Wsg2 : Wmg2;
    const float* __restrict__ b2 = g ? bsg2 : bmg2;
    const float* __restrict__ ev = evidence + b * (NT * ND) + t0 * ND;

    float h[6];
    #pragma unroll
    for (int t = 0; t < 6; ++t) h[t] = 0.0f;

    const int ibase = ih * 64;
    #pragma unroll 8
    for (int ii = 0; ii < 64; ++ii) {
        const int i = ibase + ii;
        float w = W1[i * ND + j];
        #pragma unroll
        for (int t = 0; t < 6; ++t) h[t] += ev[t * ND + i] * w;
    }

    if (ih > 0) {
        #pragma unroll
        for (int t = 0; t < 6; ++t) part[ih - 1][t][j] = h[t];
    }
    __syncthreads();
    if (ih == 0) {
        const float b1j = b1[j], w2j = W2[j];
        #pragma unroll
        for (int t = 0; t < 6; ++t) {
            float v = gelu_exact(h[t] + part[0][t][j] + part[1][t][j] +
                                 part[2][t][j] + b1j) * w2j;
            #pragma unroll
            for (int off = 32; off > 0; off >>= 1) v += __shfl_down(v, off, 64);
            if (lane == 0) red[wv][t] = v;
        }
    }
    __syncthreads();
    if (tid < 6) {
        float s = red[0][tid] + red[1][tid] + red[2][tid] + red[3][tid] + b2[0];
        gates[g * (NB * NT) + b * NT + t0 + tid] = sigmoidf_(s);
    }
}

// ---------------------------------------------------------------------------
// K2: sparse graph readout. grid = 64 (block/batch), 512 threads. map/step
// memories never materialized (<=12 nonzeros each). Walk propagated by 12
// threads via LDS atomics; acc lists gathered split-half with 4-wide prefetch.
// ---------------------------------------------------------------------------
__global__ __launch_bounds__(512) void k_readout(
    const int* __restrict__ marker, const int* __restrict__ srci,
    const int* __restrict__ srcv, const int* __restrict__ tsymi,
    const int* __restrict__ tsymv, const int* __restrict__ tvali,
    const int* __restrict__ tvalv, const int* __restrict__ qidx,
    const int* __restrict__ qvld,
    const float* __restrict__ symbol_emb, const float* __restrict__ value_emb,
    const float* __restrict__ gates,
    float* __restrict__ gs)   // [B][512] = concat(acc_s, acc_v@value_emb)
{
    const int b = blockIdx.x, tid = threadIdx.x;
    __shared__ float walk[NS], nxt[NS];
    __shared__ int   esrc[NT], etsym[NT], etval[NT];
    __shared__ float mapw[NT], stepw[NT];
    __shared__ int   sidx[64]; __shared__ float sval[64];
    __shared__ int   vidx[64]; __shared__ float vval[64];
    __shared__ int   scnt, vcnt;

    walk[tid] = 0.f; nxt[tid] = 0.f;
    if (tid == 0) { scnt = 0; vcnt = 0; }
    if (tid < NT) {
        int e = b * NT + tid;
        int mk = marker[e];
        int sv_ = srcv[e], tsv_ = tsymv[e], tvv_ = tvalv[e];
        esrc[tid]  = min(max(srci[e], 0), NS - 1);
        etsym[tid] = min(max(tsymi[e], 0), NS - 1);
        etval[tid] = min(max(tvali[e], 0), NV - 1);
        bool mmask = ((mk == 0) || (mk == 1)) && (sv_ > 0) && (tvv_ > 0);
        bool smask = (mk == 2) && (sv_ > 0) && (tsv_ > 0);
        mapw[tid]  = mmask ? gates[0 * (NB * NT) + e] : 0.f;
        stepw[tid] = smask ? gates[1 * (NB * NT) + e] : 0.f;
    }
    __syncthreads();
    if (tid == 0) {
        int qc = min(max(qidx[b], 0), NS - 1);
        float qv = (float)qvld[b];
        walk[qc] = qv;
        if (qv != 0.f) { sidx[0] = qc; sval[0] = qv; scnt = 1; }
    }
    __syncthreads();
    if (tid < NT) {   // stage 0: acc_v from initial walk
        float c = walk[esrc[tid]] * mapw[tid];
        if (c != 0.f) { int k = atomicAdd(&vcnt, 1); vidx[k] = etval[tid]; vval[k] = c; }
    }
    __syncthreads();
    for (int stp = 0; stp < 3; ++stp) {
        if (tid < NT) {
            float c = walk[esrc[tid]] * stepw[tid];
            if (c != 0.f) {
                atomicAdd(&nxt[etsym[tid]], c);
                int k = atomicAdd(&scnt, 1); sidx[k] = etsym[tid]; sval[k] = c;
            }
        }
        __syncthreads();
        { float a = nxt[tid]; walk[tid] = a; nxt[tid] = 0.f; }
        __syncthreads();
        if (tid < NT) {
            float c = walk[esrc[tid]] * mapw[tid];
            if (c != 0.f) { int k = atomicAdd(&vcnt, 1); vidx[k] = etval[tid]; vval[k] = c; }
        }
        __syncthreads();
    }
    const int d = tid & 255;
    const float* __restrict__ emb  = (tid < 256) ? symbol_emb : value_emb;
    const int*   idxl = (tid < 256) ? sidx : vidx;
    const float* vall = (tid < 256) ? sval : vval;
    const int n = (tid < 256) ? scnt : vcnt;
    float acc = 0.f;
    int k = 0;
    for (; k + 4 <= n; k += 4) {
        int   i0 = idxl[k],     i1 = idxl[k + 1], i2 = idxl[k + 2], i3 = idxl[k + 3];
        float w0 = vall[k],     w1 = vall[k + 1], w2 = vall[k + 2], w3 = vall[k + 3];
        float r0 = emb[i0 * ND + d], r1 = emb[i1 * ND + d];
        float r2 = emb[i2 * ND + d], r3 = emb[i3 * ND + d];
        acc += w0 * r0; acc += w1 * r1; acc += w2 * r2; acc += w3 * r3;
    }
    for (; k < n; ++k) acc += vall[k] * emb[idxl[k] * ND + d];
    gs[b * 512 + (tid < 256 ? 0 : 256) + d] = acc;
}

// ---------------------------------------------------------------------------
// K3: first MLP layers. grid = (2 mats x 4 j-slices x 8 b-tiles) = 64 blocks,
// 512 threads: i split across thread halves, LDS pair-reduce.
// ---------------------------------------------------------------------------
__global__ __launch_bounds__(512) void k_mlp1(
    const float* __restrict__ gs,
    const float* __restrict__ Wo1, const float* __restrict__ bo1,
    const float* __restrict__ Wf1, const float* __restrict__ bf1,
    float* __restrict__ H)  // [2][B][256]
{
    const int blk = blockIdx.x;
    const int m = blk >> 5;
    const int r = blk & 31;
    const int js = r >> 3, bt = r & 7;
    const int tid = threadIdx.x;
    const int lane = tid & 63;
    const int bsub = (tid >> 6) & 3;
    const int ih = tid >> 8;
    const int j = js * 64 + lane;
    const int b0 = bt * 8 + bsub * 2, b1_ = b0 + 1;

    const float* __restrict__ W1   = (m ? Wf1 : Wo1) + ih * 256 * 256;
    const float* __restrict__ bias = m ? bf1 : bo1;
    const float* __restrict__ x0 = gs + b0 * 512 + ih * 256;
    const float* __restrict__ x1 = gs + b1_ * 512 + ih * 256;

    float a0 = 0.f, a1 = 0.f;
    #pragma unroll 8
    for (int i = 0; i < 256; ++i) {
        float w = W1[i * 256 + j];
        a0 += x0[i] * w; a1 += x1[i] * w;
    }
    __shared__ float part[256][2];
    if (ih == 1) { part[tid & 255][0] = a0; part[tid & 255][1] = a1; }
    __syncthreads();
    if (ih == 0) {
        float bj = bias[j];
        H[m * (NB * 256) + b0 * 256 + j]  = gelu_exact(a0 + part[tid][0] + bj);
        H[m * (NB * 256) + b1_ * 256 + j] = gelu_exact(a1 + part[tid][1] + bj);
    }
}

// ---------------------------------------------------------------------------
// K4: second MLP layers. blocks 0..63: logits (64x512); 64..95: feedback
// (64x256). 512 threads, k split across halves + LDS pair-reduce.
// ---------------------------------------------------------------------------
__global__ __launch_bounds__(512) void k_mlp2(
    const float* __restrict__ H,
    const float* __restrict__ Wo2, const float* __restrict__ bo2,
    const float* __restrict__ Wf2, const float* __restrict__ bf2,
    float* __restrict__ out)  // [logits 64*512 | feedback 64*256]
{
    const int blk = blockIdx.x;
    const int tid = threadIdx.x;
    const int lane = tid & 63;
    const int bsub = (tid >> 6) & 3;
    const int ih = tid >> 8;
    __shared__ float part[256][2];

    if (blk < 64) {
        const int bt = blk >> 3, vs = blk & 7;
        const int v = vs * 64 + lane;
        const int b0 = bt * 8 + bsub * 2, b1_ = b0 + 1;
        const float* __restrict__ h0 = H + b0 * 256 + ih * 128;
        const float* __restrict__ h1 = H + b1_ * 256 + ih * 128;
        const float* __restrict__ Wp = Wo2 + ih * 128 * 512;
        float a0 = 0.f, a1 = 0.f;
        #pragma unroll 8
        for (int k = 0; k < 128; ++k) {
            float w = Wp[k * 512 + v];
            a0 += h0[k] * w; a1 += h1[k] * w;
        }
        if (ih == 1) { part[tid & 255][0] = a0; part[tid & 255][1] = a1; }
        __syncthreads();
        if (ih == 0) {
            float bv = bo2[v];
            out[b0 * 512 + v]  = a0 + part[tid][0] + bv;
            out[b1_ * 512 + v] = a1 + part[tid][1] + bv;
        }
    } else {
        const int r = blk - 64;
        const int bt = r >> 2, ds = r & 3;
        const int d = ds * 64 + lane;
        const int b0 = bt * 8 + bsub * 2, b1_ = b0 + 1;
        const float* __restrict__ h0 = H + (NB * 256) + b0 * 256 + ih * 128;
        const float* __restrict__ h1 = H + (NB * 256) + b1_ * 256 + ih * 128;
        const float* __restrict__ Wp = Wf2 + ih * 128 * 256;
        float a0 = 0.f, a1 = 0.f;
        #pragma unroll 8
        for (int k = 0; k < 128; ++k) {
            float w = Wp[k * 256 + d];
            a0 += h0[k] * w; a1 += h1[k] * w;
        }
        if (ih == 1) { part[tid & 255][0] = a0; part[tid & 255][1] = a1; }
        __syncthreads();
        if (ih == 0) {
            float bd = bf2[d];
            out[NB * NV + b0 * 256 + d]  = a0 + part[tid][0] + bd;
            out[NB * NV + b1_ * 256 + d] = a1 + part[tid][1] + bd;
        }
    }
}

extern "C" void kernel_launch(void* const* d_in, const int* in_sizes, int n_in,
                              void* d_out, int out_size, void* d_ws, size_t ws_size,
                              hipStream_t stream) {
    const int* event_marker       = (const int*)d_in[0];
    const int* source_idx         = (const int*)d_in[1];
    const int* source_valid       = (const int*)d_in[2];
    const int* target_symbol_idx  = (const int*)d_in[3];
    const int* target_symbol_vld  = (const int*)d_in[4];
    const int* target_value_idx   = (const int*)d_in[5];
    const int* target_value_vld   = (const int*)d_in[6];
    const int* query_idx          = (const int*)d_in[7];
    const int* query_valid        = (const int*)d_in[8];
    const float* evidence   = (const float*)d_in[9];
    const float* symbol_emb = (const float*)d_in[10];
    const float* value_emb  = (const float*)d_in[11];
    const float* Wmg1 = (const float*)d_in[12]; const float* bmg1 = (const float*)d_in[13];
    const float* Wmg2 = (const float*)d_in[14]; const float* bmg2 = (const float*)d_in[15];
    const float* Wsg1 = (const float*)d_in[16]; const float* bsg1 = (const float*)d_in[17];
    const float* Wsg2 = (const float*)d_in[18]; const float* bsg2 = (const float*)d_in[19];
    const float* Wf1  = (const float*)d_in[20]; const float* bf1  = (const float*)d_in[21];
    const float* Wf2  = (const float*)d_in[22]; const float* bf2  = (const float*)d_in[23];
    const float* Wo1  = (const float*)d_in[24]; const float* bo1  = (const float*)d_in[25];
    const float* Wo2  = (const float*)d_in[26]; const float* bo2  = (const float*)d_in[27];

    float* ws    = (float*)d_ws;
    float* gates = ws;                  // [2][768]
    float* gs    = ws + 2048;           // [64][512]
    float* H     = ws + 2048 + 32768;   // [2][64][256]

    k_gates<<<dim3(256), dim3(1024), 0, stream>>>(
        evidence, Wmg1, bmg1, Wmg2, bmg2, Wsg1, bsg1, Wsg2, bsg2, gates);
    k_readout<<<dim3(64), dim3(512), 0, stream>>>(
        event_marker, source_idx, source_valid, target_symbol_idx,
        target_symbol_vld, target_value_idx, target_value_vld,
        query_idx, query_valid, symbol_emb, value_emb, gates, gs);
    k_mlp1<<<dim3(64), dim3(512), 0, stream>>>(gs, Wo1, bo1, Wf1, bf1, H);
    k_mlp2<<<dim3(96), dim3(512), 0, stream>>>(H, Wo2, bo2, Wf2, bf2, (float*)d_out);
}